// Round 10
// baseline (72.164 us; speedup 1.0000x reference)
//
#include <hip/hip_runtime.h>
#include <stdint.h>

// AugmentationPipeline: bit-exact JAX threefry (partitionable path) on device.
// Round 10: HETEROGENEOUS SPLIT into two kernels.
//  Kernel A (streaming): crop + reorder + lens -- near-pure streaming like the
//    harness fill kernel (no mask threefry, no select machinery).
//  Kernel B (compute):   mask only -- threefry in load shadow, 128-bin radix
//    select, no LDS row staging at all (rank uses dedicated s_bin; stores use
//    registers). seq re-read is L3-hot after A.
// Out layout (int32): mask_seq[B*L] | mask_len[B] | crop_seq[B*L] | crop_len[B]
//                     | reord_seq[B*L] | reord_len[B]

#define NB 32768
#define NL 512
#define NBL (NB * NL)

struct AugKeys {
  uint32_t km0, km1;   // mask key
  uint32_t kc0, kc1;   // crop key
  uint32_t r10, r11;   // reorder k1 (wsize)
  uint32_t r20, r21;   // reorder k2 (start)
  uint32_t r30, r31;   // reorder k3 (apply)
  uint32_t r40, r41;   // reorder k4 (window keys, shape (B,5))
};

__host__ __device__ __forceinline__ uint32_t rotl32(uint32_t x, uint32_t r) {
  return (x << r) | (x >> (32u - r));
}

// Threefry-2x32, 20 rounds (JAX's threefry2x32_p).
__host__ __device__ inline void tf2x32(uint32_t k0, uint32_t k1,
                                       uint32_t x0, uint32_t x1,
                                       uint32_t& o0, uint32_t& o1) {
  const uint32_t ks2 = k0 ^ k1 ^ 0x1BD11BDAu;
#define TFR(r) { x0 += x1; x1 = rotl32(x1, r); x1 ^= x0; }
  x0 += k0; x1 += k1;
  TFR(13u) TFR(15u) TFR(26u) TFR(6u)
  x0 += k1; x1 += ks2 + 1u;
  TFR(17u) TFR(29u) TFR(16u) TFR(24u)
  x0 += ks2; x1 += k0 + 2u;
  TFR(13u) TFR(15u) TFR(26u) TFR(6u)
  x0 += k0; x1 += k1 + 3u;
  TFR(17u) TFR(29u) TFR(16u) TFR(24u)
  x0 += k1; x1 += ks2 + 4u;
  TFR(13u) TFR(15u) TFR(26u) TFR(6u)
  x0 += ks2; x1 += k0 + 5u;
#undef TFR
  o0 = x0; o1 = x1;
}

// JAX uniform(0,1) from 32 random bits.
__device__ __forceinline__ float u01f(uint32_t bits) {
  return __uint_as_float((bits >> 9) | 0x3F800000u) - 1.0f;
}

// 32-bit random bits for flat element index i (partitionable threefry):
// xor-fold of the two output words of block (hi=0, lo=i).
__device__ __forceinline__ uint32_t rbits32(uint32_t k0, uint32_t k1, uint32_t i) {
  uint32_t o0, o1;
  tf2x32(k0, k1, 0u, i, o0, o1);
  return o0 ^ o1;
}

// ======================= Kernel A: crop + reorder + lens =====================
__global__ void __launch_bounds__(256)
aug_stream(const int* __restrict__ seq, const int* __restrict__ lens,
           int* __restrict__ out, AugKeys K)
{
  __shared__ int s_row[4][NL];

  const int t = threadIdx.x;
  const int w = t >> 6;        // row-in-block (wave id)
  const int l = t & 63;        // lane
  const int b = blockIdx.x * 4 + w;
  const int len = __builtin_amdgcn_readfirstlane(lens[b]);
  const int* rowp = seq + (size_t)b * NL;

  // strided loads + LDS stage (stride-1 across lanes: no conflicts)
  int es[8];
#pragma unroll
  for (int it = 0; it < 8; ++it) es[it] = rowp[(it << 6) + l];

  // load shadow: per-row uniforms (lanes 0..8)
  float uval = 0.f;
  if (l < 9) {
    uint32_t kk0, kk1, f;
    if (l == 0)      { kk0 = K.kc0; kk1 = K.kc1; f = (uint32_t)b; }
    else if (l == 1) { kk0 = K.r10; kk1 = K.r11; f = (uint32_t)b; }
    else if (l == 2) { kk0 = K.r20; kk1 = K.r21; f = (uint32_t)b; }
    else if (l == 3) { kk0 = K.r30; kk1 = K.r31; f = (uint32_t)b; }
    else             { kk0 = K.r40; kk1 = K.r41; f = (uint32_t)b * 5u + (uint32_t)(l - 4); }
    uval = u01f(rbits32(kk0, kk1, f));
  }
  const float u_c = __shfl(uval, 0);
  const float u_w = __shfl(uval, 1);
  const float u_s = __shfl(uval, 2);
  const float u_a = __shfl(uval, 3);
  float u4[5];
#pragma unroll
  for (int k = 0; k < 5; ++k) u4[k] = __shfl(uval, 4 + k);

#pragma unroll
  for (int it = 0; it < 8; ++it) s_row[w][(it << 6) + l] = es[it];

  // n_valid (ballot/popcount)
  int nv = 0;
#pragma unroll
  for (int it = 0; it < 8; ++it) {
    nv += (int)__popcll(__ballot(((it << 6) + l < len) && (es[it] != 0)));
  }
  const int n_valid = __builtin_amdgcn_readfirstlane(nv);

  __builtin_amdgcn_wave_barrier();   // s_row staged (same-wave LDS in-order)

  // ---- crop: rotated conflict-free LDS gather, strided store ----
  const int clen = min(max(3, (int)((float)len * 0.8f)), len);
  const int cms = max(len - clen + 1, 1);
  const int cstart = (int)(u_c * (float)cms);
  const bool apply_c = (len > 3);
  {
    int* cout = out + (size_t)NBL + NB + (size_t)b * NL;
#pragma unroll
    for (int it = 0; it < 8; ++it) {
      const int pos = (it << 6) + l;
      const int g = s_row[w][min(cstart + pos, NL - 1)];
      cout[pos] = apply_c ? ((pos < clen) ? g : 0) : es[it];
    }
  }

  // ---- lens outputs ----
  if (l == 0) {
    out[(size_t)NBL + b] = len;                             // mask_len
    out[2 * (size_t)NBL + NB + b] = apply_c ? clen : len;   // crop_len
    out[3 * (size_t)NBL + 2 * NB + b] = len;                // reord_len
  }

  // ---- reorder: 5 uniform-address broadcast LDS reads, patch strided copy ----
  const int max_w = min(n_valid, 5);
  int wsize = 2 + (int)(u_w * (float)max(max_w - 1, 1));
  wsize = min(max(wsize, 2), 5);
  const int rms = max(n_valid - wsize + 1, 1);
  const int rstart = (int)(u_s * (float)rms);
  const bool apply_r = (len > 2) && (u_a <= 0.3f) && (n_valid >= 2);

  int cols[5], items[5];
  float fk[5];
#pragma unroll
  for (int k = 0; k < 5; ++k) {
    cols[k] = min(rstart + k, NL - 1);          // valid_idx is identity
    items[k] = s_row[w][cols[k]];               // uniform addr: broadcast read
    fk[k] = (k < wsize) ? u4[k] : __int_as_float(0x7F800000);
  }
  // stable argsort of 5 via ranks (static indexing only)
  int rank5[5];
#pragma unroll
  for (int k = 0; k < 5; ++k) {
    int rr = 0;
#pragma unroll
    for (int j = 0; j < 5; ++j) {
      rr += ((fk[j] < fk[k]) || (fk[j] == fk[k] && j < k)) ? 1 : 0;
    }
    rank5[k] = rr;
  }
  int valk[5];
#pragma unroll
  for (int p = 0; p < 5; ++p) {
    int sh = items[0];
#pragma unroll
    for (int k = 0; k < 5; ++k) if (rank5[k] == p) sh = items[k];
    valk[p] = (apply_r && p < wsize) ? sh : items[p];
  }

  int r8[8] = {es[0], es[1], es[2], es[3], es[4], es[5], es[6], es[7]};
#pragma unroll
  for (int k = 0; k < 5; ++k) {  // ascending k: last dup write wins (XLA scatter order)
    const int ck = cols[k];
#pragma unroll
    for (int it = 0; it < 8; ++it) {
      if ((ck >> 6) == it && (ck & 63) == l) r8[it] = valk[k];
    }
  }
  int* rout = out + 2 * (size_t)NBL + 2 * NB + (size_t)b * NL;
#pragma unroll
  for (int it = 0; it < 8; ++it) rout[(it << 6) + l] = r8[it];
}

// ============================ Kernel B: mask =================================
__global__ void __launch_bounds__(256)
aug_mask(const int* __restrict__ seq, const int* __restrict__ lens,
         int* __restrict__ out, AugKeys K)
{
  __shared__ int s_hist[4][128];
  __shared__ uint32_t s_bin[4][NL];
  __shared__ int s_nbin[4];

  const int t = threadIdx.x;
  const int w = t >> 6;        // row-in-block (wave id)
  const int l = t & 63;        // lane
  const int b = blockIdx.x * 4 + w;
  const int len = __builtin_amdgcn_readfirstlane(lens[b]);
  const int* rowp = seq + (size_t)b * NL;

  // issue strided loads (L3-hot after kernel A)
  int es[8];
#pragma unroll
  for (int it = 0; it < 8; ++it) es[it] = rowp[(it << 6) + l];

  s_hist[w][2 * l] = 0;
  s_hist[w][2 * l + 1] = 0;
  if (l == 0) s_nbin[w] = 0;

  // ---- load shadow: mask threefry (depends only on b/pos/len) ----
  // Pair-branched (granularity 128): two independent 20-round chains (ILP=2).
  // key = (bits & ~0x1FF) | pos: monotone == (score, idx), unique.
  uint32_t kk[8] = {0u, 0u, 0u, 0u, 0u, 0u, 0u, 0u};
  const uint32_t fbase = (uint32_t)b * NL;
#pragma unroll
  for (int p = 0; p < 4; ++p) {
    if ((p << 7) < len) {                      // wave-uniform (scalar) skip
      const int posA = (p << 7) + l;
      const int posB = (p << 7) + 64 + l;
      const uint32_t bitsA = rbits32(K.km0, K.km1, fbase + (uint32_t)posA);
      const uint32_t bitsB = rbits32(K.km0, K.km1, fbase + (uint32_t)posB);
      kk[2 * p]     = (bitsA & 0xFFFFFE00u) | (uint32_t)posA;
      kk[2 * p + 1] = (bitsB & 0xFFFFFE00u) | (uint32_t)posB;
    }
  }

  // ---- first use of es: validity + n_valid ----
  uint32_t vsm = 0;
  int nv = 0;
#pragma unroll
  for (int it = 0; it < 8; ++it) {
    const bool vs = ((it << 6) + l < len) && (es[it] != 0);
    vsm |= (uint32_t)vs << it;
    nv += (int)__popcll(__ballot(vs));
  }
  const int n_valid = __builtin_amdgcn_readfirstlane(nv);

  // histogram atomics (keys already in registers)
#pragma unroll
  for (int it = 0; it < 8; ++it) {
    if ((vsm >> it) & 1) atomicAdd(&s_hist[w][kk[it] >> 25], 1);
  }
  __builtin_amdgcn_wave_barrier();

  // ---- 128-bin scan, 2 bins/lane, pure shuffle ----
  const int h0 = s_hist[w][2 * l];
  const int h1 = s_hist[w][2 * l + 1];
  const int pair = h0 + h1;
  int incl = pair;
#pragma unroll
  for (int d = 1; d < 64; d <<= 1) {
    const int o = __shfl_up(incl, d);
    if (l >= d) incl += o;
  }
  const int ex0 = incl - pair;
  const int ex1 = ex0 + h0;
  const int n_mask = min(max(1, (int)((float)n_valid * 0.2f)), n_valid);
  const bool c0 = (h0 > 0) && (ex0 < n_mask) && (n_mask <= ex0 + h0);
  const bool c1 = (h1 > 0) && (ex1 < n_mask) && (n_mask <= ex1 + h1);
  const unsigned long long B0 = __ballot(c0);
  const unsigned long long B1 = __ballot(c1);
  int tbin = -1, below = 0;
  if (B0) {
    const int tl = __ffsll(B0) - 1;
    tbin = 2 * tl; below = __shfl(ex0, tl);
  } else if (B1) {
    const int tl = __ffsll(B1) - 1;
    tbin = 2 * tl + 1; below = __shfl(ex1, tl);
  }
  const int need = n_mask - below;

  // ---- compact in-bin keys (atomic append; order irrelevant) ----
#pragma unroll
  for (int it = 0; it < 8; ++it) {
    if (((vsm >> it) & 1) && (int)(kk[it] >> 25) == tbin) {
      s_bin[w][atomicAdd(&s_nbin[w], 1)] = kk[it];
    }
  }
  __builtin_amdgcn_wave_barrier();
  const int mtot = s_nbin[w];

  // ---- single rank pass over the threshold bin (broadcast LDS reads) ----
  int rk[8] = {0, 0, 0, 0, 0, 0, 0, 0};
  for (int j = 0; j < mtot; ++j) {
    const uint32_t bk = s_bin[w][j];
#pragma unroll
    for (int it = 0; it < 8; ++it) rk[it] += (bk < kk[it]) ? 1 : 0;
  }

  // ---- mask output: strided dword stores (256B coalesced per instruction) ----
  const bool apply_m = (len > 1) && (n_valid > 0);
  int* mout = out + (size_t)b * NL;
#pragma unroll
  for (int it = 0; it < 8; ++it) {
    const int bin = (int)(kk[it] >> 25);
    const bool dm = apply_m && ((vsm >> it) & 1) &&
                    (bin < tbin || (bin == tbin && rk[it] < need));
    mout[(it << 6) + l] = dm ? 0 : es[it];   // MASK_TOKEN = 0
  }
}

extern "C" void kernel_launch(void* const* d_in, const int* in_sizes, int n_in,
                              void* d_out, int out_size, void* d_ws, size_t ws_size,
                              hipStream_t stream) {
  const int* seq  = (const int*)d_in[0];
  const int* lens = (const int*)d_in[1];
  int* out = (int*)d_out;

  // key(42) = (0, 42). Partitionable (fold-like) split:
  // child i = full threefry block (counts hi=0, lo=i), key = (o0, o1).
  AugKeys K;
  uint32_t kr0, kr1;
  tf2x32(0u, 42u, 0u, 0u, K.km0, K.km1);  // km
  tf2x32(0u, 42u, 0u, 1u, K.kc0, K.kc1);  // kc
  tf2x32(0u, 42u, 0u, 2u, kr0, kr1);      // kr
  tf2x32(kr0, kr1, 0u, 0u, K.r10, K.r11); // k1
  tf2x32(kr0, kr1, 0u, 1u, K.r20, K.r21); // k2
  tf2x32(kr0, kr1, 0u, 2u, K.r30, K.r31); // k3
  tf2x32(kr0, kr1, 0u, 3u, K.r40, K.r41); // k4

  aug_stream<<<dim3(NB / 4), dim3(256), 0, stream>>>(seq, lens, out, K);
  aug_mask  <<<dim3(NB / 4), dim3(256), 0, stream>>>(seq, lens, out, K);
}

// Round 11
// 71.794 us; speedup vs baseline: 1.0052x; 1.0052x over previous
//
#include <hip/hip_runtime.h>
#include <stdint.h>

// AugmentationPipeline: bit-exact JAX threefry (partitionable path) on device.
// Round 11: HETEROGENEOUS CO-RESIDENT BLOCKS in one launch (R10's split ran
// serially on the stream -- no overlap). role = blockIdx.x & 1:
//   even: streaming role (crop + reorder + lens; memory-heavy, light VALU)
//   odd:  mask role (threefry + 128-bin radix select; VALU-heavy, 1/3 stores)
// Alternating roles => every CU holds a mix at every dispatch point, so the
// memory pipe (streaming blocks) and VALU pipe (mask blocks) run concurrently.
// Out layout (int32): mask_seq[B*L] | mask_len[B] | crop_seq[B*L] | crop_len[B]
//                     | reord_seq[B*L] | reord_len[B]

#define NB 32768
#define NL 512
#define NBL (NB * NL)

struct AugKeys {
  uint32_t km0, km1;   // mask key
  uint32_t kc0, kc1;   // crop key
  uint32_t r10, r11;   // reorder k1 (wsize)
  uint32_t r20, r21;   // reorder k2 (start)
  uint32_t r30, r31;   // reorder k3 (apply)
  uint32_t r40, r41;   // reorder k4 (window keys, shape (B,5))
};

__host__ __device__ __forceinline__ uint32_t rotl32(uint32_t x, uint32_t r) {
  return (x << r) | (x >> (32u - r));
}

// Threefry-2x32, 20 rounds (JAX's threefry2x32_p).
__host__ __device__ inline void tf2x32(uint32_t k0, uint32_t k1,
                                       uint32_t x0, uint32_t x1,
                                       uint32_t& o0, uint32_t& o1) {
  const uint32_t ks2 = k0 ^ k1 ^ 0x1BD11BDAu;
#define TFR(r) { x0 += x1; x1 = rotl32(x1, r); x1 ^= x0; }
  x0 += k0; x1 += k1;
  TFR(13u) TFR(15u) TFR(26u) TFR(6u)
  x0 += k1; x1 += ks2 + 1u;
  TFR(17u) TFR(29u) TFR(16u) TFR(24u)
  x0 += ks2; x1 += k0 + 2u;
  TFR(13u) TFR(15u) TFR(26u) TFR(6u)
  x0 += k0; x1 += k1 + 3u;
  TFR(17u) TFR(29u) TFR(16u) TFR(24u)
  x0 += k1; x1 += ks2 + 4u;
  TFR(13u) TFR(15u) TFR(26u) TFR(6u)
  x0 += ks2; x1 += k0 + 5u;
#undef TFR
  o0 = x0; o1 = x1;
}

// JAX uniform(0,1) from 32 random bits.
__device__ __forceinline__ float u01f(uint32_t bits) {
  return __uint_as_float((bits >> 9) | 0x3F800000u) - 1.0f;
}

// 32-bit random bits for flat element index i (partitionable threefry):
// xor-fold of the two output words of block (hi=0, lo=i).
__device__ __forceinline__ uint32_t rbits32(uint32_t k0, uint32_t k1, uint32_t i) {
  uint32_t o0, o1;
  tf2x32(k0, k1, 0u, i, o0, o1);
  return o0 ^ o1;
}

__global__ void __launch_bounds__(256)
aug_hetero(const int* __restrict__ seq, const int* __restrict__ lens,
           int* __restrict__ out, AugKeys K)
{
  // union of both roles' LDS needs (role is block-uniform; 10.5KB/block,
  // 8 blocks/CU still thread-limited)
  __shared__ int s_row[4][NL];          // stream: staged row | mask: bin buffer
  __shared__ int s_hist[4][128];        // mask only
  __shared__ int s_nbin[4];             // mask only

  const int role = blockIdx.x & 1;
  const int bg = blockIdx.x >> 1;
  const int t = threadIdx.x;
  const int w = t >> 6;        // row-in-block (wave id)
  const int l = t & 63;        // lane
  const int b = bg * 4 + w;
  const int len = __builtin_amdgcn_readfirstlane(lens[b]);
  const int* rowp = seq + (size_t)b * NL;

  // strided loads: es[it] = seq[b*512 + it*64 + l]  (8 x 256B coalesced)
  int es[8];
#pragma unroll
  for (int it = 0; it < 8; ++it) es[it] = rowp[(it << 6) + l];

  if (role == 0) {
    // ==================== streaming role: crop + reorder + lens ====================
    // load shadow: per-row uniforms (lanes 0..8)
    float uval = 0.f;
    if (l < 9) {
      uint32_t kk0, kk1, f;
      if (l == 0)      { kk0 = K.kc0; kk1 = K.kc1; f = (uint32_t)b; }
      else if (l == 1) { kk0 = K.r10; kk1 = K.r11; f = (uint32_t)b; }
      else if (l == 2) { kk0 = K.r20; kk1 = K.r21; f = (uint32_t)b; }
      else if (l == 3) { kk0 = K.r30; kk1 = K.r31; f = (uint32_t)b; }
      else             { kk0 = K.r40; kk1 = K.r41; f = (uint32_t)b * 5u + (uint32_t)(l - 4); }
      uval = u01f(rbits32(kk0, kk1, f));
    }
    const float u_c = __shfl(uval, 0);
    const float u_w = __shfl(uval, 1);
    const float u_s = __shfl(uval, 2);
    const float u_a = __shfl(uval, 3);
    float u4[5];
#pragma unroll
    for (int k = 0; k < 5; ++k) u4[k] = __shfl(uval, 4 + k);

    // stage row into wave-private LDS (stride-1 across lanes: no conflicts)
#pragma unroll
    for (int it = 0; it < 8; ++it) s_row[w][(it << 6) + l] = es[it];

    // n_valid (ballot/popcount)
    int nv = 0;
#pragma unroll
    for (int it = 0; it < 8; ++it) {
      nv += (int)__popcll(__ballot(((it << 6) + l < len) && (es[it] != 0)));
    }
    const int n_valid = __builtin_amdgcn_readfirstlane(nv);

    __builtin_amdgcn_wave_barrier();   // s_row staged (same-wave LDS in-order)

    // ---- crop: rotated conflict-free LDS gather, strided store ----
    const int clen = min(max(3, (int)((float)len * 0.8f)), len);
    const int cms = max(len - clen + 1, 1);
    const int cstart = (int)(u_c * (float)cms);
    const bool apply_c = (len > 3);
    {
      int* cout = out + (size_t)NBL + NB + (size_t)b * NL;
#pragma unroll
      for (int it = 0; it < 8; ++it) {
        const int pos = (it << 6) + l;
        const int g = s_row[w][min(cstart + pos, NL - 1)];
        cout[pos] = apply_c ? ((pos < clen) ? g : 0) : es[it];
      }
    }

    // ---- lens outputs ----
    if (l == 0) {
      out[(size_t)NBL + b] = len;                             // mask_len
      out[2 * (size_t)NBL + NB + b] = apply_c ? clen : len;   // crop_len
      out[3 * (size_t)NBL + 2 * NB + b] = len;                // reord_len
    }

    // ---- reorder: 5 uniform-address broadcast LDS reads, patch strided copy ----
    const int max_w = min(n_valid, 5);
    int wsize = 2 + (int)(u_w * (float)max(max_w - 1, 1));
    wsize = min(max(wsize, 2), 5);
    const int rms = max(n_valid - wsize + 1, 1);
    const int rstart = (int)(u_s * (float)rms);
    const bool apply_r = (len > 2) && (u_a <= 0.3f) && (n_valid >= 2);

    int cols[5], items[5];
    float fk[5];
#pragma unroll
    for (int k = 0; k < 5; ++k) {
      cols[k] = min(rstart + k, NL - 1);          // valid_idx is identity
      items[k] = s_row[w][cols[k]];               // uniform addr: broadcast read
      fk[k] = (k < wsize) ? u4[k] : __int_as_float(0x7F800000);
    }
    // stable argsort of 5 via ranks (static indexing only)
    int rank5[5];
#pragma unroll
    for (int k = 0; k < 5; ++k) {
      int rr = 0;
#pragma unroll
      for (int j = 0; j < 5; ++j) {
        rr += ((fk[j] < fk[k]) || (fk[j] == fk[k] && j < k)) ? 1 : 0;
      }
      rank5[k] = rr;
    }
    int valk[5];
#pragma unroll
    for (int p = 0; p < 5; ++p) {
      int sh = items[0];
#pragma unroll
      for (int k = 0; k < 5; ++k) if (rank5[k] == p) sh = items[k];
      valk[p] = (apply_r && p < wsize) ? sh : items[p];
    }

    int r8[8] = {es[0], es[1], es[2], es[3], es[4], es[5], es[6], es[7]};
#pragma unroll
    for (int k = 0; k < 5; ++k) {  // ascending k: last dup write wins (XLA scatter order)
      const int ck = cols[k];
#pragma unroll
      for (int it = 0; it < 8; ++it) {
        if ((ck >> 6) == it && (ck & 63) == l) r8[it] = valk[k];
      }
    }
    int* rout = out + 2 * (size_t)NBL + 2 * NB + (size_t)b * NL;
#pragma unroll
    for (int it = 0; it < 8; ++it) rout[(it << 6) + l] = r8[it];

  } else {
    // ============================ mask role ============================
    s_hist[w][2 * l] = 0;
    s_hist[w][2 * l + 1] = 0;
    if (l == 0) s_nbin[w] = 0;

    // ---- load shadow: mask threefry (depends only on b/pos/len) ----
    // Pair-branched (granularity 128): two independent 20-round chains (ILP=2).
    // key = (bits & ~0x1FF) | pos: monotone == (score, idx), unique.
    uint32_t kk[8] = {0u, 0u, 0u, 0u, 0u, 0u, 0u, 0u};
    const uint32_t fbase = (uint32_t)b * NL;
#pragma unroll
    for (int p = 0; p < 4; ++p) {
      if ((p << 7) < len) {                      // wave-uniform (scalar) skip
        const int posA = (p << 7) + l;
        const int posB = (p << 7) + 64 + l;
        const uint32_t bitsA = rbits32(K.km0, K.km1, fbase + (uint32_t)posA);
        const uint32_t bitsB = rbits32(K.km0, K.km1, fbase + (uint32_t)posB);
        kk[2 * p]     = (bitsA & 0xFFFFFE00u) | (uint32_t)posA;
        kk[2 * p + 1] = (bitsB & 0xFFFFFE00u) | (uint32_t)posB;
      }
    }

    // ---- first use of es: validity + n_valid ----
    uint32_t vsm = 0;
    int nv = 0;
#pragma unroll
    for (int it = 0; it < 8; ++it) {
      const bool vs = ((it << 6) + l < len) && (es[it] != 0);
      vsm |= (uint32_t)vs << it;
      nv += (int)__popcll(__ballot(vs));
    }
    const int n_valid = __builtin_amdgcn_readfirstlane(nv);

    // histogram atomics (keys already in registers)
#pragma unroll
    for (int it = 0; it < 8; ++it) {
      if ((vsm >> it) & 1) atomicAdd(&s_hist[w][kk[it] >> 25], 1);
    }
    __builtin_amdgcn_wave_barrier();

    // ---- 128-bin scan, 2 bins/lane, pure shuffle ----
    const int h0 = s_hist[w][2 * l];
    const int h1 = s_hist[w][2 * l + 1];
    const int pair = h0 + h1;
    int incl = pair;
#pragma unroll
    for (int d = 1; d < 64; d <<= 1) {
      const int o = __shfl_up(incl, d);
      if (l >= d) incl += o;
    }
    const int ex0 = incl - pair;
    const int ex1 = ex0 + h0;
    const int n_mask = min(max(1, (int)((float)n_valid * 0.2f)), n_valid);
    const bool c0 = (h0 > 0) && (ex0 < n_mask) && (n_mask <= ex0 + h0);
    const bool c1 = (h1 > 0) && (ex1 < n_mask) && (n_mask <= ex1 + h1);
    const unsigned long long B0 = __ballot(c0);
    const unsigned long long B1 = __ballot(c1);
    int tbin = -1, below = 0;
    if (B0) {
      const int tl = __ffsll(B0) - 1;
      tbin = 2 * tl; below = __shfl(ex0, tl);
    } else if (B1) {
      const int tl = __ffsll(B1) - 1;
      tbin = 2 * tl + 1; below = __shfl(ex1, tl);
    }
    const int need = n_mask - below;

    // ---- compact in-bin keys into s_row-alias (atomic append) ----
    uint32_t* s_bin = reinterpret_cast<uint32_t*>(s_row[w]);
#pragma unroll
    for (int it = 0; it < 8; ++it) {
      if (((vsm >> it) & 1) && (int)(kk[it] >> 25) == tbin) {
        s_bin[atomicAdd(&s_nbin[w], 1)] = kk[it];
      }
    }
    __builtin_amdgcn_wave_barrier();
    const int mtot = s_nbin[w];

    // ---- single rank pass over the threshold bin (broadcast LDS reads) ----
    int rk[8] = {0, 0, 0, 0, 0, 0, 0, 0};
    for (int j = 0; j < mtot; ++j) {
      const uint32_t bk = s_bin[j];
#pragma unroll
      for (int it = 0; it < 8; ++it) rk[it] += (bk < kk[it]) ? 1 : 0;
    }

    // ---- mask output: strided dword stores (256B coalesced per instruction) ----
    const bool apply_m = (len > 1) && (n_valid > 0);
    int* mout = out + (size_t)b * NL;
#pragma unroll
    for (int it = 0; it < 8; ++it) {
      const int bin = (int)(kk[it] >> 25);
      const bool dm = apply_m && ((vsm >> it) & 1) &&
                      (bin < tbin || (bin == tbin && rk[it] < need));
      mout[(it << 6) + l] = dm ? 0 : es[it];   // MASK_TOKEN = 0
    }
  }
}

extern "C" void kernel_launch(void* const* d_in, const int* in_sizes, int n_in,
                              void* d_out, int out_size, void* d_ws, size_t ws_size,
                              hipStream_t stream) {
  const int* seq  = (const int*)d_in[0];
  const int* lens = (const int*)d_in[1];
  int* out = (int*)d_out;

  // key(42) = (0, 42). Partitionable (fold-like) split:
  // child i = full threefry block (counts hi=0, lo=i), key = (o0, o1).
  AugKeys K;
  uint32_t kr0, kr1;
  tf2x32(0u, 42u, 0u, 0u, K.km0, K.km1);  // km
  tf2x32(0u, 42u, 0u, 1u, K.kc0, K.kc1);  // kc
  tf2x32(0u, 42u, 0u, 2u, kr0, kr1);      // kr
  tf2x32(kr0, kr1, 0u, 0u, K.r10, K.r11); // k1
  tf2x32(kr0, kr1, 0u, 1u, K.r20, K.r21); // k2
  tf2x32(kr0, kr1, 0u, 2u, K.r30, K.r31); // k3
  tf2x32(kr0, kr1, 0u, 3u, K.r40, K.r41); // k4

  aug_hetero<<<dim3(NB / 2), dim3(256), 0, stream>>>(seq, lens, out, K);
}

// Round 12
// 59.861 us; speedup vs baseline: 1.2055x; 1.1994x over previous
//
#include <hip/hip_runtime.h>
#include <stdint.h>

// AugmentationPipeline: bit-exact JAX threefry (partitionable path) on device.
// FINAL (= round 7, best measured 60.18 us): LDS row staging in STRIDED
// layout; crop = conflict-free rotated LDS gather; reorder window via 5
// uniform-address broadcast LDS reads. All three outputs strided dword
// stores. s_bin aliases s_row. One wave per row, zero s_barriers.
// R8-R11 post-mortems: chunk-pairing, 128-blocks, load-shadow hoist, serial
// split, and co-resident hetero blocks all measured neutral-to-worse; this
// fused structure is the plateau (~1.5x the pure-write floor).
// Out layout (int32): mask_seq[B*L] | mask_len[B] | crop_seq[B*L] | crop_len[B]
//                     | reord_seq[B*L] | reord_len[B]

#define NB 32768
#define NL 512
#define NBL (NB * NL)

struct AugKeys {
  uint32_t km0, km1;   // mask key
  uint32_t kc0, kc1;   // crop key
  uint32_t r10, r11;   // reorder k1 (wsize)
  uint32_t r20, r21;   // reorder k2 (start)
  uint32_t r30, r31;   // reorder k3 (apply)
  uint32_t r40, r41;   // reorder k4 (window keys, shape (B,5))
};

__host__ __device__ __forceinline__ uint32_t rotl32(uint32_t x, uint32_t r) {
  return (x << r) | (x >> (32u - r));
}

// Threefry-2x32, 20 rounds (JAX's threefry2x32_p).
__host__ __device__ inline void tf2x32(uint32_t k0, uint32_t k1,
                                       uint32_t x0, uint32_t x1,
                                       uint32_t& o0, uint32_t& o1) {
  const uint32_t ks2 = k0 ^ k1 ^ 0x1BD11BDAu;
#define TFR(r) { x0 += x1; x1 = rotl32(x1, r); x1 ^= x0; }
  x0 += k0; x1 += k1;
  TFR(13u) TFR(15u) TFR(26u) TFR(6u)
  x0 += k1; x1 += ks2 + 1u;
  TFR(17u) TFR(29u) TFR(16u) TFR(24u)
  x0 += ks2; x1 += k0 + 2u;
  TFR(13u) TFR(15u) TFR(26u) TFR(6u)
  x0 += k0; x1 += k1 + 3u;
  TFR(17u) TFR(29u) TFR(16u) TFR(24u)
  x0 += k1; x1 += ks2 + 4u;
  TFR(13u) TFR(15u) TFR(26u) TFR(6u)
  x0 += ks2; x1 += k0 + 5u;
#undef TFR
  o0 = x0; o1 = x1;
}

// JAX uniform(0,1) from 32 random bits.
__device__ __forceinline__ float u01f(uint32_t bits) {
  return __uint_as_float((bits >> 9) | 0x3F800000u) - 1.0f;
}

// 32-bit random bits for flat element index i (partitionable threefry):
// xor-fold of the two output words of block (hi=0, lo=i).
__device__ __forceinline__ uint32_t rbits32(uint32_t k0, uint32_t k1, uint32_t i) {
  uint32_t o0, o1;
  tf2x32(k0, k1, 0u, i, o0, o1);
  return o0 ^ o1;
}

__global__ void __launch_bounds__(256)
aug_pipeline(const int* __restrict__ seq, const int* __restrict__ lens,
             int* __restrict__ out, AugKeys K)
{
  __shared__ int s_row[4][NL];       // staged row; aliased as bin buffer later
  __shared__ int s_hist[4][128];
  __shared__ int s_nbin[4];

  const int t = threadIdx.x;
  const int w = t >> 6;        // row-in-block (wave id)
  const int l = t & 63;        // lane
  const int b = blockIdx.x * 4 + w;
  const int len = __builtin_amdgcn_readfirstlane(lens[b]);   // wave-uniform scalar
  const int* rowp = seq + (size_t)b * NL;

  // strided loads: es[it] = seq[b*512 + it*64 + l]  (8 x 256B coalesced)
  int es[8];
#pragma unroll
  for (int it = 0; it < 8; ++it) es[it] = rowp[(it << 6) + l];

  // stage row into wave-private LDS, strided (stride-1 across lanes: no conflicts)
#pragma unroll
  for (int it = 0; it < 8; ++it) s_row[w][(it << 6) + l] = es[it];

  // init wave-private hist early (in-order LDS, overlaps with compute below)
  s_hist[w][2 * l] = 0;
  s_hist[w][2 * l + 1] = 0;
  if (l == 0) s_nbin[w] = 0;

  // per-row uniforms (lanes 0..8), broadcast via shfl
  float uval = 0.f;
  if (l < 9) {
    uint32_t kk0, kk1, f;
    if (l == 0)      { kk0 = K.kc0; kk1 = K.kc1; f = (uint32_t)b; }
    else if (l == 1) { kk0 = K.r10; kk1 = K.r11; f = (uint32_t)b; }
    else if (l == 2) { kk0 = K.r20; kk1 = K.r21; f = (uint32_t)b; }
    else if (l == 3) { kk0 = K.r30; kk1 = K.r31; f = (uint32_t)b; }
    else             { kk0 = K.r40; kk1 = K.r41; f = (uint32_t)b * 5u + (uint32_t)(l - 4); }
    uval = u01f(rbits32(kk0, kk1, f));
  }
  const float u_c = __shfl(uval, 0);
  const float u_w = __shfl(uval, 1);
  const float u_s = __shfl(uval, 2);
  const float u_a = __shfl(uval, 3);
  float u4[5];
#pragma unroll
  for (int k = 0; k < 5; ++k) u4[k] = __shfl(uval, 4 + k);

  // strided validity + n_valid (ballot/popcount, scalar pipe)
  uint32_t vsm = 0;
  int nv = 0;
#pragma unroll
  for (int it = 0; it < 8; ++it) {
    const bool vs = ((it << 6) + l < len) && (es[it] != 0);
    vsm |= (uint32_t)vs << it;
    nv += (int)__popcll(__ballot(vs));
  }
  const int n_valid = __builtin_amdgcn_readfirstlane(nv);

  __builtin_amdgcn_wave_barrier();   // s_row staged (same-wave LDS is in-order)

  // ---- crop: rotated conflict-free LDS gather, strided store ----
  const int clen = min(max(3, (int)((float)len * 0.8f)), len);
  const int cms = max(len - clen + 1, 1);
  const int cstart = (int)(u_c * (float)cms);
  const bool apply_c = (len > 3);
  {
    int* cout = out + (size_t)NBL + NB + (size_t)b * NL;
#pragma unroll
    for (int it = 0; it < 8; ++it) {
      const int pos = (it << 6) + l;
      const int g = s_row[w][min(cstart + pos, NL - 1)];  // lane-stride 1: no conflict
      const int c = apply_c ? ((pos < clen) ? g : 0) : es[it];
      cout[pos] = c;
    }
  }

  // ---- lens outputs (early) ----
  if (l == 0) {
    out[(size_t)NBL + b] = len;                             // mask_len
    out[2 * (size_t)NBL + NB + b] = apply_c ? clen : len;   // crop_len
    out[3 * (size_t)NBL + 2 * NB + b] = len;                // reord_len
  }

  // ---- reorder: 5 uniform-address broadcast LDS reads, patch strided copy ----
  {
    const int max_w = min(n_valid, 5);
    int wsize = 2 + (int)(u_w * (float)max(max_w - 1, 1));
    wsize = min(max(wsize, 2), 5);
    const int rms = max(n_valid - wsize + 1, 1);
    const int rstart = (int)(u_s * (float)rms);
    const bool apply_r = (len > 2) && (u_a <= 0.3f) && (n_valid >= 2);

    int cols[5], items[5];
    float fk[5];
#pragma unroll
    for (int k = 0; k < 5; ++k) {
      cols[k] = min(rstart + k, NL - 1);          // valid_idx is identity
      items[k] = s_row[w][cols[k]];               // uniform addr: broadcast read
      fk[k] = (k < wsize) ? u4[k] : __int_as_float(0x7F800000);
    }
    // stable argsort of 5 via ranks (static indexing only)
    int rank5[5];
#pragma unroll
    for (int k = 0; k < 5; ++k) {
      int rr = 0;
#pragma unroll
      for (int j = 0; j < 5; ++j) {
        rr += ((fk[j] < fk[k]) || (fk[j] == fk[k] && j < k)) ? 1 : 0;
      }
      rank5[k] = rr;
    }
    int valk[5];
#pragma unroll
    for (int p = 0; p < 5; ++p) {
      int sh = items[0];
#pragma unroll
      for (int k = 0; k < 5; ++k) if (rank5[k] == p) sh = items[k];
      valk[p] = (apply_r && p < wsize) ? sh : items[p];
    }

    int r8[8] = {es[0], es[1], es[2], es[3], es[4], es[5], es[6], es[7]};
#pragma unroll
    for (int k = 0; k < 5; ++k) {  // ascending k: last dup write wins (XLA scatter order)
      const int ck = cols[k];
#pragma unroll
      for (int it = 0; it < 8; ++it) {
        if ((ck >> 6) == it && (ck & 63) == l) r8[it] = valk[k];
      }
    }
    int* rout = out + 2 * (size_t)NBL + 2 * NB + (size_t)b * NL;
#pragma unroll
    for (int it = 0; it < 8; ++it) rout[(it << 6) + l] = r8[it];
  }

  // ---- pass A: strided threefry + histogram; chunks past len skipped (scalar) ----
  // key = (bits & ~0x1FF) | pos : monotone == (score, idx), unique.
  uint32_t kk[8] = {0u, 0u, 0u, 0u, 0u, 0u, 0u, 0u};
#pragma unroll
  for (int it = 0; it < 8; ++it) {
    if ((it << 6) < len) {                     // wave-uniform (scalar) skip
      const int pos = (it << 6) + l;
      const uint32_t bits = rbits32(K.km0, K.km1, (uint32_t)b * NL + (uint32_t)pos);
      kk[it] = (bits & 0xFFFFFE00u) | (uint32_t)pos;
      if ((vsm >> it) & 1) atomicAdd(&s_hist[w][kk[it] >> 25], 1);
    }
  }
  __builtin_amdgcn_wave_barrier();

  // ---- 128-bin scan, 2 bins/lane, pure shuffle ----
  const int h0 = s_hist[w][2 * l];
  const int h1 = s_hist[w][2 * l + 1];
  const int pair = h0 + h1;
  int incl = pair;
#pragma unroll
  for (int d = 1; d < 64; d <<= 1) {
    const int o = __shfl_up(incl, d);
    if (l >= d) incl += o;
  }
  const int ex0 = incl - pair;
  const int ex1 = ex0 + h0;
  const int n_mask = min(max(1, (int)((float)n_valid * 0.2f)), n_valid);
  const bool c0 = (h0 > 0) && (ex0 < n_mask) && (n_mask <= ex0 + h0);
  const bool c1 = (h1 > 0) && (ex1 < n_mask) && (n_mask <= ex1 + h1);
  const unsigned long long B0 = __ballot(c0);
  const unsigned long long B1 = __ballot(c1);
  int tbin = -1, below = 0;
  if (B0) {
    const int tl = __ffsll(B0) - 1;
    tbin = 2 * tl; below = __shfl(ex0, tl);
  } else if (B1) {
    const int tl = __ffsll(B1) - 1;
    tbin = 2 * tl + 1; below = __shfl(ex1, tl);
  }
  const int need = n_mask - below;

  // ---- pass B: compact in-bin keys into s_row (row is dead now) ----
  uint32_t* s_bin = reinterpret_cast<uint32_t*>(s_row[w]);
#pragma unroll
  for (int it = 0; it < 8; ++it) {
    if (((vsm >> it) & 1) && (int)(kk[it] >> 25) == tbin) {
      s_bin[atomicAdd(&s_nbin[w], 1)] = kk[it];
    }
  }
  __builtin_amdgcn_wave_barrier();
  const int mtot = s_nbin[w];

  // ---- single rank pass over the threshold bin (broadcast LDS reads) ----
  int rk[8] = {0, 0, 0, 0, 0, 0, 0, 0};
  for (int j = 0; j < mtot; ++j) {
    const uint32_t bk = s_bin[j];
#pragma unroll
    for (int it = 0; it < 8; ++it) rk[it] += (bk < kk[it]) ? 1 : 0;
  }

  // ---- mask output: strided dword stores (256B coalesced per instruction) ----
  const bool apply_m = (len > 1) && (n_valid > 0);
  int* mout = out + (size_t)b * NL;
#pragma unroll
  for (int it = 0; it < 8; ++it) {
    const int bin = (int)(kk[it] >> 25);
    const bool dm = apply_m && ((vsm >> it) & 1) &&
                    (bin < tbin || (bin == tbin && rk[it] < need));
    mout[(it << 6) + l] = dm ? 0 : es[it];   // MASK_TOKEN = 0
  }
}

extern "C" void kernel_launch(void* const* d_in, const int* in_sizes, int n_in,
                              void* d_out, int out_size, void* d_ws, size_t ws_size,
                              hipStream_t stream) {
  const int* seq  = (const int*)d_in[0];
  const int* lens = (const int*)d_in[1];
  int* out = (int*)d_out;

  // key(42) = (0, 42). Partitionable (fold-like) split:
  // child i = full threefry block (counts hi=0, lo=i), key = (o0, o1).
  AugKeys K;
  uint32_t kr0, kr1;
  tf2x32(0u, 42u, 0u, 0u, K.km0, K.km1);  // km
  tf2x32(0u, 42u, 0u, 1u, K.kc0, K.kc1);  // kc
  tf2x32(0u, 42u, 0u, 2u, kr0, kr1);      // kr
  tf2x32(kr0, kr1, 0u, 0u, K.r10, K.r11); // k1
  tf2x32(kr0, kr1, 0u, 1u, K.r20, K.r21); // k2
  tf2x32(kr0, kr1, 0u, 2u, K.r30, K.r31); // k3
  tf2x32(kr0, kr1, 0u, 3u, K.r40, K.r41); // k4

  aug_pipeline<<<dim3(NB / 4), dim3(256), 0, stream>>>(seq, lens, out, K);
}